// Round 1
// baseline (448.452 us; speedup 1.0000x reference)
//
#include <hip/hip_runtime.h>
#include <hip/hip_bf16.h>

// ---------------- constants ----------------
constexpr int Bc   = 2;
constexpr int Sc   = 2048;
constexpr int Hc   = 1024;   // HIDDEN
constexpr int Dc   = 2048;   // MLP
constexpr int NST  = 16;     // N_STATE
constexpr int DTR  = 64;     // DT_RANK
constexpr int Mrows = Bc * Sc;   // 4096
constexpr int NCH  = 32;         // scan chunks
constexpr int CL   = Sc / NCH;   // 64 steps per chunk

typedef __attribute__((ext_vector_type(8))) short short8;
typedef __attribute__((ext_vector_type(4))) float float4v;

__device__ __forceinline__ short f2bf(float f) {
    unsigned int u = __builtin_bit_cast(unsigned int, f);
    u += 0x7fffu + ((u >> 16) & 1u);      // RNE
    return (short)(u >> 16);
}

// ---------------- fp32 -> bf16 straight convert (x) ----------------
__global__ __launch_bounds__(256) void convert_bf16(const float* __restrict__ in,
                                                    short* __restrict__ out, int n4) {
    int i = blockIdx.x * 256 + threadIdx.x;
    if (i >= n4) return;
    const float4 v = *(const float4*)(in + (size_t)i * 4);
    short4 o;
    o.x = f2bf(v.x); o.y = f2bf(v.y); o.z = f2bf(v.z); o.w = f2bf(v.w);
    *(short4*)(out + (size_t)i * 4) = o;
}

// ---------------- fp32 [K][N] -> bf16 [N][K] transpose-convert ----------------
__global__ __launch_bounds__(256) void transpose_bf16(const float* __restrict__ in,
                                                      short* __restrict__ out,
                                                      int K, int N) {
    __shared__ float tile[32][33];
    int n0 = blockIdx.x * 32, k0 = blockIdx.y * 32;
    int tx = threadIdx.x & 31, ty = threadIdx.x >> 5;   // 32 x 8
    for (int r = ty; r < 32; r += 8)
        tile[r][tx] = in[(size_t)(k0 + r) * N + n0 + tx];
    __syncthreads();
    for (int r = ty; r < 32; r += 8)
        out[(size_t)(n0 + r) * K + k0 + tx] = f2bf(tile[tx][r]);
}

// ---------------- main bf16 GEMM: C = A(MxK) * Bt(NxK)^T, fp32 out ----------------
// EPI: 0=linear(+bias) 1=sigmoid(+bias) 2=softplus(+bias)
template<int EPI>
__global__ __launch_bounds__(256) void gemm_bt(const short* __restrict__ A,
                                               const short* __restrict__ Bt,
                                               const float* __restrict__ bias,
                                               float* __restrict__ out,
                                               int M, int N, int K) {
    constexpr int BK = 32;
    constexpr int LDT = 40;                 // padded LDS stride (80 B, 16B-aligned)
    __shared__ short As[128 * LDT];
    __shared__ short Bs[128 * LDT];
    const int tid  = threadIdx.x;
    const int lane = tid & 63, w = tid >> 6;
    const int wm = (w >> 1) * 64, wn = (w & 1) * 64;
    const int l15 = lane & 15, quad = lane >> 4;
    const int bm0 = blockIdx.y * 128, bn0 = blockIdx.x * 128;

    float4v acc[4][4] = {};
    const int row = tid >> 1;               // 0..127
    const int c0  = (tid & 1) * 16;         // 0 or 16

    for (int k0 = 0; k0 < K; k0 += BK) {
        const short* ga = A  + (size_t)(bm0 + row) * K + k0 + c0;
        const short* gb = Bt + (size_t)(bn0 + row) * K + k0 + c0;
        int4 av0 = *(const int4*)(ga);
        int4 av1 = *(const int4*)(ga + 8);
        int4 bv0 = *(const int4*)(gb);
        int4 bv1 = *(const int4*)(gb + 8);
        __syncthreads();
        *(int4*)&As[row * LDT + c0]     = av0;
        *(int4*)&As[row * LDT + c0 + 8] = av1;
        *(int4*)&Bs[row * LDT + c0]     = bv0;
        *(int4*)&Bs[row * LDT + c0 + 8] = bv1;
        __syncthreads();
        short8 af[4], bf[4];
        #pragma unroll
        for (int i = 0; i < 4; i++)
            af[i] = *(const short8*)&As[(wm + i * 16 + l15) * LDT + quad * 8];
        #pragma unroll
        for (int j = 0; j < 4; j++)
            bf[j] = *(const short8*)&Bs[(wn + j * 16 + l15) * LDT + quad * 8];
        #pragma unroll
        for (int i = 0; i < 4; i++)
            #pragma unroll
            for (int j = 0; j < 4; j++)
                acc[i][j] = __builtin_amdgcn_mfma_f32_16x16x32_bf16(af[i], bf[j], acc[i][j], 0, 0, 0);
    }

    #pragma unroll
    for (int i = 0; i < 4; i++) {
        #pragma unroll
        for (int j = 0; j < 4; j++) {
            const int col = bn0 + wn + j * 16 + l15;
            const float bs = bias[col];
            #pragma unroll
            for (int r = 0; r < 4; r++) {
                const int rw = bm0 + wm + i * 16 + quad * 4 + r;
                float v = acc[i][j][r] + bs;
                if (EPI == 1) v = 1.f / (1.f + __expf(-v));
                else if (EPI == 2) v = fmaxf(v, 0.f) + log1pf(__expf(-fabsf(v)));
                out[(size_t)rw * N + col] = v;
            }
        }
    }
}

// ---------------- depthwise causal conv + sigmoid ----------------
__global__ __launch_bounds__(256) void conv_sig(const float* __restrict__ upre,
                                                const float* __restrict__ cw,
                                                const float* __restrict__ cb,
                                                float* __restrict__ u,
                                                short* __restrict__ ub, int total) {
    int idx = blockIdx.x * 256 + threadIdx.x;
    if (idx >= total) return;
    int d = idx & (Dc - 1);
    int s = (idx >> 11) & (Sc - 1);
    float acc = cb[d];
    #pragma unroll
    for (int k = 0; k < 4; k++) {
        int si = s + k - 3;
        float v = (si >= 0) ? upre[idx + (k - 3) * Dc] : 0.f;
        acc = fmaf(v, cw[(d << 2) + k], acc);
    }
    float y = 1.f / (1.f + __expf(-acc));
    u[idx] = y;
    ub[idx] = f2bf(y);
}

// ---------------- xp GEMM: ub(4096x2048) @ xpwt^T(96x2048) -> split outputs ----------------
__global__ __launch_bounds__(256) void xp_gemm(const short* __restrict__ ub,
                                               const short* __restrict__ xpwt,
                                               short* __restrict__ xpdt,
                                               float* __restrict__ bc) {
    const int tid = threadIdx.x, lane = tid & 63, w = tid >> 6;
    const int m0 = (blockIdx.x * 4 + w) * 16;
    const int l15 = lane & 15, quad = lane >> 4;
    float4v acc[6] = {};
    const short* arow = ub + (size_t)(m0 + l15) * Dc + quad * 8;
    for (int k0 = 0; k0 < Dc; k0 += 32) {
        short8 a = *(const short8*)(arow + k0);
        #pragma unroll
        for (int j = 0; j < 6; j++) {
            short8 b = *(const short8*)(xpwt + (size_t)(j * 16 + l15) * Dc + k0 + quad * 8);
            acc[j] = __builtin_amdgcn_mfma_f32_16x16x32_bf16(a, b, acc[j], 0, 0, 0);
        }
    }
    #pragma unroll
    for (int j = 0; j < 6; j++) {
        const int col = j * 16 + l15;
        #pragma unroll
        for (int r = 0; r < 4; r++) {
            const int rw = m0 + quad * 4 + r;
            float v = acc[j][r];
            if (col < DTR) xpdt[(size_t)rw * DTR + col] = f2bf(v);
            else           bc[(size_t)rw * 32 + (col - DTR)] = v;
        }
    }
}

// ---------------- scan pass A: chunk-local scan + dA products ----------------
__global__ __launch_bounds__(256) void scan_a(const float* __restrict__ delta,
                                              const float* __restrict__ u,
                                              const float* __restrict__ bc,
                                              const float* __restrict__ A_log,
                                              float* __restrict__ P,
                                              float* __restrict__ Q) {
    __shared__ float bm[CL * NST];
    const int tid = threadIdx.x;
    const int chunk = blockIdx.x, dblk = blockIdx.y, b = blockIdx.z;
    const int d = dblk * 256 + tid;
    const int t0 = chunk * CL;
    for (int i = tid; i < CL * NST; i += 256) {
        int tl = i >> 4, n = i & 15;
        bm[i] = bc[(size_t)(b * Sc + t0 + tl) * 32 + n];
    }
    float Areg[NST];
    #pragma unroll
    for (int n = 0; n < NST; n++) Areg[n] = -__expf(A_log[d * NST + n]);
    __syncthreads();
    float h[NST], p[NST];
    #pragma unroll
    for (int n = 0; n < NST; n++) { h[n] = 0.f; p[n] = 1.f; }
    for (int t = 0; t < CL; t++) {
        size_t idx = (size_t)(b * Sc + t0 + t) * Dc + d;
        float dl = delta[idx];
        float du = dl * u[idx];
        #pragma unroll
        for (int n = 0; n < NST; n++) {
            float dA = __expf(dl * Areg[n]);
            h[n] = fmaf(dA, h[n], bm[t * NST + n] * du);
            p[n] *= dA;
        }
    }
    size_t base = ((size_t)(b * Dc + d) * NCH + chunk) * NST;
    #pragma unroll
    for (int n = 0; n < NST; n++) { P[base + n] = p[n]; Q[base + n] = h[n]; }
}

// ---------------- scan pass B: combine carries across chunks (in-place -> Hin in Q) ----
__global__ __launch_bounds__(256) void scan_b(const float* __restrict__ P,
                                              float* __restrict__ Q) {
    int t = blockIdx.x * 256 + threadIdx.x;     // B*D*16 = 65536
    int n = t & 15;
    int bd = t >> 4;
    size_t base = (size_t)bd * NCH * NST + n;
    float carry = 0.f;
    for (int c = 0; c < NCH; c++) {
        size_t o = base + (size_t)c * NST;
        float p = P[o], q = Q[o];
        Q[o] = carry;                            // exclusive carry = chunk's initial h
        carry = fmaf(p, carry, q);
    }
}

// ---------------- scan pass C: fixup + y, fused (y + u*D)*gate -> bf16 ----------------
__global__ __launch_bounds__(256) void scan_c(const float* __restrict__ delta,
                                              const float* __restrict__ u,
                                              const float* __restrict__ gate,
                                              const float* __restrict__ bc,
                                              const float* __restrict__ A_log,
                                              const float* __restrict__ Dskip,
                                              const float* __restrict__ Hin,
                                              short* __restrict__ zb) {
    __shared__ float bm[CL * NST];
    __shared__ float cm[CL * NST];
    const int tid = threadIdx.x;
    const int chunk = blockIdx.x, dblk = blockIdx.y, b = blockIdx.z;
    const int d = dblk * 256 + tid;
    const int t0 = chunk * CL;
    for (int i = tid; i < CL * NST; i += 256) {
        int tl = i >> 4, n = i & 15;
        size_t o = (size_t)(b * Sc + t0 + tl) * 32;
        bm[i] = bc[o + n];
        cm[i] = bc[o + 16 + n];
    }
    float Areg[NST];
    #pragma unroll
    for (int n = 0; n < NST; n++) Areg[n] = -__expf(A_log[d * NST + n]);
    const float Dd = Dskip[d];
    float h[NST];
    size_t hbase = ((size_t)(b * Dc + d) * NCH + chunk) * NST;
    #pragma unroll
    for (int n = 0; n < NST; n++) h[n] = Hin[hbase + n];
    __syncthreads();
    for (int t = 0; t < CL; t++) {
        size_t idx = (size_t)(b * Sc + t0 + t) * Dc + d;
        float dl = delta[idx];
        float uu = u[idx];
        float g  = gate[idx];
        float du = dl * uu;
        float y = 0.f;
        #pragma unroll
        for (int n = 0; n < NST; n++) {
            float dA = __expf(dl * Areg[n]);
            h[n] = fmaf(dA, h[n], bm[t * NST + n] * du);
            y = fmaf(h[n], cm[t * NST + n], y);
        }
        zb[idx] = f2bf((y + uu * Dd) * g);
    }
}

// ---------------- host launcher ----------------
extern "C" void kernel_launch(void* const* d_in, const int* in_sizes, int n_in,
                              void* d_out, int out_size, void* d_ws, size_t ws_size,
                              hipStream_t stream) {
    const float* x    = (const float*)d_in[0];
    const float* W1   = (const float*)d_in[1];
    const float* b1   = (const float*)d_in[2];
    const float* W2   = (const float*)d_in[3];
    const float* b2   = (const float*)d_in[4];
    const float* cw   = (const float*)d_in[5];
    const float* cb   = (const float*)d_in[6];
    const float* A_log= (const float*)d_in[7];
    const float* xpw  = (const float*)d_in[8];
    const float* dtw  = (const float*)d_in[9];
    const float* dtb  = (const float*)d_in[10];
    const float* Dsk  = (const float*)d_in[11];
    const float* Wo   = (const float*)d_in[12];
    const float* bo   = (const float*)d_in[13];
    float* out = (float*)d_out;

    // workspace carve-up (256B aligned)
    char* w = (char*)d_ws;
    auto alloc = [&](size_t bytes) {
        void* p = (void*)w;
        w += (bytes + 255) & ~(size_t)255;
        return p;
    };
    short* xb    = (short*)alloc((size_t)Mrows * Hc * 2);        // x bf16
    short* w1t   = (short*)alloc((size_t)Dc * Hc * 2);           // W1^T bf16 [2048][1024]
    short* w2t   = (short*)alloc((size_t)Dc * Hc * 2);
    short* wot   = (short*)alloc((size_t)Hc * Dc * 2);           // Wo^T bf16 [1024][2048]
    short* xpwt  = (short*)alloc((size_t)96 * Dc * 2);           // x_proj_w^T [96][2048]
    short* dtwt  = (short*)alloc((size_t)Dc * DTR * 2);          // dt_proj_w^T [2048][64]
    float* u_pre = (float*)alloc((size_t)Mrows * Dc * 4);        // also reused as delta
    float* gate  = (float*)alloc((size_t)Mrows * Dc * 4);
    float* ubuf  = (float*)alloc((size_t)Mrows * Dc * 4);
    short* ub    = (short*)alloc((size_t)Mrows * Dc * 2);
    short* xpdt  = (short*)alloc((size_t)Mrows * DTR * 2);
    float* bcbuf = (float*)alloc((size_t)Mrows * 32 * 4);
    float* Pbuf  = (float*)alloc((size_t)Bc * Dc * NCH * NST * 4);
    float* Qbuf  = (float*)alloc((size_t)Bc * Dc * NCH * NST * 4);
    short* zb    = (short*)alloc((size_t)Mrows * Dc * 2);
    float* delta = u_pre;   // reuse: u_pre dead after conv

    // 1. converts / transposes
    convert_bf16<<<dim3((Mrows * Hc / 4 + 255) / 256), 256, 0, stream>>>(x, xb, Mrows * Hc / 4);
    transpose_bf16<<<dim3(Dc / 32, Hc / 32), 256, 0, stream>>>(W1, w1t, Hc, Dc);
    transpose_bf16<<<dim3(Dc / 32, Hc / 32), 256, 0, stream>>>(W2, w2t, Hc, Dc);
    transpose_bf16<<<dim3(Hc / 32, Dc / 32), 256, 0, stream>>>(Wo, wot, Dc, Hc);
    transpose_bf16<<<dim3(96 / 32, Dc / 32), 256, 0, stream>>>(xpw, xpwt, Dc, 96);
    transpose_bf16<<<dim3(Dc / 32, DTR / 32), 256, 0, stream>>>(dtw, dtwt, DTR, Dc);

    // 2. u_pre = x@W1 + b1 ; gate = sigmoid(x@W2 + b2)
    gemm_bt<0><<<dim3(Dc / 128, Mrows / 128), 256, 0, stream>>>(xb, w1t, b1, u_pre, Mrows, Dc, Hc);
    gemm_bt<1><<<dim3(Dc / 128, Mrows / 128), 256, 0, stream>>>(xb, w2t, b2, gate, Mrows, Dc, Hc);

    // 3. u = sigmoid(causal depthwise conv(u_pre))
    const int total = Mrows * Dc;
    conv_sig<<<dim3((total + 255) / 256), 256, 0, stream>>>(u_pre, cw, cb, ubuf, ub, total);

    // 4. xp = u @ x_proj_w  -> xpdt (bf16, first 64 cols), bc (fp32, B/C 32 cols)
    xp_gemm<<<dim3(Mrows / 64), 256, 0, stream>>>(ub, xpwt, xpdt, bcbuf);

    // 5. delta = softplus(xpdt @ dt_proj_w + dtb)   (overwrites u_pre region)
    gemm_bt<2><<<dim3(Dc / 128, Mrows / 128), 256, 0, stream>>>(xpdt, dtwt, dtb, delta, Mrows, Dc, DTR);

    // 6. chunked selective scan
    scan_a<<<dim3(NCH, Dc / 256, Bc), 256, 0, stream>>>(delta, ubuf, bcbuf, A_log, Pbuf, Qbuf);
    scan_b<<<dim3(Bc * Dc * NST / 256), 256, 0, stream>>>(Pbuf, Qbuf);
    scan_c<<<dim3(NCH, Dc / 256, Bc), 256, 0, stream>>>(delta, ubuf, gate, bcbuf, A_log, Dsk, Qbuf, zb);

    // 7. out = zb @ Wo + bo
    gemm_bt<0><<<dim3(Hc / 128, Mrows / 128), 256, 0, stream>>>(zb, wot, bo, out, Mrows, Hc, Dc);
}